// Round 13
// baseline (263.868 us; speedup 1.0000x reference)
//
#include <hip/hip_runtime.h>
#include <hip/hip_bf16.h>

typedef __hip_bfloat16 bf16;
typedef unsigned short u16;
typedef __attribute__((ext_vector_type(8))) short bf16x8;
typedef __attribute__((ext_vector_type(4))) float f32x4;

#define NB   2
#define NG   192
#define DD   256
#define NN2  (NG*NG)          // 36864
#define MT   (NB*NN2)         // 73728

static __device__ __forceinline__ float bfu2f(u16 u){
    return __uint_as_float(((unsigned)u) << 16);
}
static __device__ __forceinline__ u16 f2bfu(float f){
    bf16 h = __float2bfloat16(f);
    return *(u16*)&h;
}

// async global->LDS, 16B/lane. LDS dest: wave-uniform base + lane*16 (linear).
static __device__ __forceinline__ void gl_lds16(const void* g, void* l){
    __builtin_amdgcn_global_load_lds(
        (const __attribute__((address_space(1))) unsigned int*)g,
        (__attribute__((address_space(3))) unsigned int*)l, 16, 0, 0);
}
// XOR swizzle (element-index bits 3-5)
static __device__ __forceinline__ int swz3(int x){ return ((x ^ (x>>3)) & 7) << 3; }

// ------------------------------------------------------------------
// cast E -> bf16, fused with bmat GEMV
// ------------------------------------------------------------------
__global__ __launch_bounds__(256) void k_cast_eb(
    const float* __restrict__ E, const float* __restrict__ Wb,
    const float* __restrict__ bb, u16* __restrict__ Eb, float* __restrict__ bm)
{
    const int t = threadIdx.x;
    size_t base = (size_t)blockIdx.x*2048 + t*8;
    float4 x = *(const float4*)(E+base);
    float4 y = *(const float4*)(E+base+4);
    ushort4 a; a.x=f2bfu(x.x); a.y=f2bfu(x.y); a.z=f2bfu(x.z); a.w=f2bfu(x.w);
    ushort4 b; b.x=f2bfu(y.x); b.y=f2bfu(y.y); b.z=f2bfu(y.z); b.w=f2bfu(y.w);
    *(ushort4*)(Eb+base)   = a;
    *(ushort4*)(Eb+base+4) = b;
    const int l32 = t & 31;
    float4 w0 = ((const float4*)Wb)[l32*2];
    float4 w1 = ((const float4*)Wb)[l32*2+1];
    float s = x.x*w0.x + x.y*w0.y + x.z*w0.z + x.w*w0.w
            + y.x*w1.x + y.y*w1.y + y.z*w1.z + y.w*w1.w;
    #pragma unroll
    for (int off=1; off<32; off<<=1) s += __shfl_xor(s, off);
    if (l32 == 0) bm[blockIdx.x*8 + (t>>5)] = s + bb[0];
}

__global__ __launch_bounds__(256) void k_cast_w(
    const float* __restrict__ Wq, const float* __restrict__ Wk,
    const float* __restrict__ Wv, const float* __restrict__ Wg,
    const float* __restrict__ Wo,
    const float* __restrict__ bq, const float* __restrict__ bk,
    const float* __restrict__ bv, const float* __restrict__ bg,
    u16* __restrict__ Wcat, u16* __restrict__ Wob, float* __restrict__ biascat)
{
    int e = blockIdx.x*256 + threadIdx.x;      // 65536 total
    Wcat[e]          = f2bfu(Wq[e]);
    Wcat[65536 + e]  = f2bfu(Wk[e]);
    Wcat[131072 + e] = f2bfu(Wv[e]);
    Wcat[196608 + e] = f2bfu(Wg[e]);
    Wob[e]           = f2bfu(Wo[e]);
    if (e < 1024){
        int p = e>>8, r = e&255;
        const float* bp = p==0?bq : p==1?bk : p==2?bv : bg;
        biascat[e] = bp[r];
    }
}

// biassym[b,i,l] = bm[b,i,l] + bm[b,l,i]
__global__ __launch_bounds__(256) void k_bias_sym(
    const float* __restrict__ bm, float* __restrict__ biassym)
{
    int rem = blockIdx.x*256 + threadIdx.x;     // < 36864
    int b = blockIdx.y;
    int i = rem / NG, l = rem % NG;
    biassym[(size_t)b*NN2 + rem] = bm[(size_t)b*NN2 + rem] + bm[(size_t)b*NN2 + l*NG + i];
}

// ------------------------------------------------------------------
// 128x128 MFMA tile, K=256, BK=32 double-buffered + counted vmcnt(4).
// (round-5/8 proven: 0 bank conflicts) — used by k_final.
// ------------------------------------------------------------------
static __device__ __forceinline__ void gemm128_dbuf(
    const u16* __restrict__ A, const u16* __restrict__ B,
    u16* As, u16* Bs, f32x4 acc[4][4], int t)
{
    const int lane = t & 63, w = t >> 6;
    const int wm = (w>>1)*64, wn = (w&1)*64;
    int offA[4], offB[4];
    #pragma unroll
    for (int f=0; f<4; f++){
        int ra = wm + f*16 + (lane&15);
        offA[f] = ra*32 + (((lane>>4) ^ ((ra>>1)&3)) << 3);
        int rb = wn + f*16 + (lane&15);
        offB[f] = rb*32 + (((lane>>4) ^ ((rb>>1)&3)) << 3);
    }
    auto stage = [&](int buf, int k0){
        #pragma unroll
        for (int it=0; it<2; it++){
            int c = it*256 + t;
            int row = c >> 2;
            int ks  = (c&3) ^ ((row>>1)&3);
            gl_lds16(A + (size_t)row*DD + k0 + ks*8, As + buf*4096 + c*8);
            gl_lds16(B + (size_t)row*DD + k0 + ks*8, Bs + buf*4096 + c*8);
        }
    };
    stage(0, 0);
    for (int ks=0; ks<8; ks++){
        if (ks<7){
            stage((ks+1)&1, (ks+1)*32);
            asm volatile("s_waitcnt vmcnt(4)" ::: "memory");
        } else {
            asm volatile("s_waitcnt vmcnt(0)" ::: "memory");
        }
        __builtin_amdgcn_s_barrier();
        const u16* Ab = As + (ks&1)*4096;
        const u16* Bb = Bs + (ks&1)*4096;
        bf16x8 a[4], b[4];
        #pragma unroll
        for (int f=0; f<4; f++) a[f] = *(const bf16x8*)(Ab + offA[f]);
        #pragma unroll
        for (int f=0; f<4; f++) b[f] = *(const bf16x8*)(Bb + offB[f]);
        #pragma unroll
        for (int mf=0; mf<4; mf++)
            #pragma unroll
            for (int nf=0; nf<4; nf++)
                acc[mf][nf] = __builtin_amdgcn_mfma_f32_16x16x32_bf16(a[mf], b[nf], acc[mf][nf], 0, 0, 0);
        __builtin_amdgcn_s_barrier();
    }
}

// ------------------------------------------------------------------
// fused q/k/v/g projection: Eb[73728x256] @ Wcat^T[1024x256]
// A staged via gl_lds (dbuf, 16KB LDS). B (weights, L2-resident) goes
// global->REGISTER directly: 3-slot rotating breg (48 VGPR live),
// loads issued 2 K-steps ahead, vmcnt(6) covers completion.
// Halves LDS traffic per K-step (48->24 KB/block) vs the LDS-B path.
// grid 4608 1D; blk&7 ~ XCD; n-tile innermost for L2 reuse of Wcat.
// ------------------------------------------------------------------
__global__ __launch_bounds__(256) void k_proj_mfma(
    const u16* __restrict__ Eb, const u16* __restrict__ Wcat,
    const float* __restrict__ biascat,
    u16* __restrict__ qb, u16* __restrict__ kb,
    u16* __restrict__ vb, u16* __restrict__ gb)
{
    __shared__ u16 As[2*4096];
    const int blk = blockIdx.x;
    const int xj = blk & 7, xi = blk >> 3;          // xi in [0,576)
    const int m0 = (xj*72 + (xi>>3)) * 128;
    const int n0 = (xi & 7) * 128;
    const int t = threadIdx.x, lane = t&63, w = t>>6;
    const int wm = (w>>1)*64, wn = (w&1)*64;

    int offA[4];
    #pragma unroll
    for (int f=0; f<4; f++){
        int ra = wm + f*16 + (lane&15);
        offA[f] = ra*32 + (((lane>>4) ^ ((ra>>1)&3)) << 3);
    }
    const u16* A = Eb + (size_t)m0*DD;
    auto stageA = [&](int buf, int k0){
        #pragma unroll
        for (int it=0; it<2; it++){
            int c = it*256 + t;
            int row = c >> 2;
            int ks  = (c&3) ^ ((row>>1)&3);
            gl_lds16(A + (size_t)row*DD + k0 + ks*8, As + buf*4096 + c*8);
        }
    };

    // B register fragments: breg[slot][f] = Wcat[(n0+wn+f*16+(lane&15))*256
    //                                            + ks*32 + (lane>>4)*8 .. +7]
    const u16* Wb0 = Wcat + (size_t)(n0 + wn + (lane&15))*DD + (lane>>4)*8;
    bf16x8 breg[3][4];
    #define LOADB(slot, kss) { \
        _Pragma("unroll") \
        for (int f=0; f<4; f++) \
            breg[slot][f] = *(const bf16x8*)(Wb0 + (size_t)f*16*DD + (kss)*32); }

    f32x4 acc[4][4];
    #pragma unroll
    for (int i=0;i<4;i++)
        #pragma unroll
        for (int j=0;j<4;j++) acc[i][j] = f32x4{0.f,0.f,0.f,0.f};

    stageA(0, 0);
    LOADB(0, 0);
    LOADB(1, 1);
    #pragma unroll
    for (int ks=0; ks<8; ks++){
        if (ks<7) stageA((ks+1)&1, (ks+1)*32);
        if (ks<6) { LOADB((ks+2)%3, ks+2); }
        if (ks<6)      asm volatile("s_waitcnt vmcnt(6)" ::: "memory");
        else if (ks==6) asm volatile("s_waitcnt vmcnt(2)" ::: "memory");
        else           asm volatile("s_waitcnt vmcnt(0)" ::: "memory");
        __builtin_amdgcn_s_barrier();
        const u16* Ab = As + (ks&1)*4096;
        bf16x8 a[4];
        #pragma unroll
        for (int f=0; f<4; f++) a[f] = *(const bf16x8*)(Ab + offA[f]);
        const int s = ks % 3;
        #pragma unroll
        for (int mf=0; mf<4; mf++)
            #pragma unroll
            for (int nf=0; nf<4; nf++)
                acc[mf][nf] = __builtin_amdgcn_mfma_f32_16x16x32_bf16(a[mf], breg[s][nf], acc[mf][nf], 0, 0, 0);
        __builtin_amdgcn_s_barrier();
    }
    #undef LOADB

    const int p = n0 >> 8;
    u16* outp = p==0?qb : p==1?kb : p==2?vb : gb;
    #pragma unroll
    for (int mf=0; mf<4; mf++){
        int m = m0 + wm + mf*16 + (lane>>4)*4;
        #pragma unroll
        for (int nf=0; nf<4; nf++){
            int gn = n0 + wn + nf*16 + (lane&15);
            float bias = biascat[gn];
            int col = gn & 255;
            #pragma unroll
            for (int r=0; r<4; r++){
                float v = acc[mf][nf][r] + bias;
                if (p==3) v = 1.0f/(1.0f+__expf(-v));
                outp[(size_t)(m+r)*DD + col] = f2bfu(v);
            }
        }
    }
}

// final: out = relu(hb @ Wob^T + bo), f32; grid 1152 1D swizzled
__global__ __launch_bounds__(256) void k_final_mfma(
    const u16* __restrict__ hb, const u16* __restrict__ Wob,
    const float* __restrict__ bo, float* __restrict__ out)
{
    __shared__ u16 As[2*4096];
    __shared__ u16 Bs[2*4096];
    const int blk = blockIdx.x;
    const int xj = blk & 7, xi = blk >> 3;          // xi in [0,144)
    const int m0 = (xj*72 + (xi>>1)) * 128;
    const int n0 = (xi & 1) * 128;
    const int t = threadIdx.x, lane = t&63, w = t>>6;
    f32x4 acc[4][4];
    #pragma unroll
    for (int i=0;i<4;i++)
        #pragma unroll
        for (int j=0;j<4;j++) acc[i][j] = f32x4{0.f,0.f,0.f,0.f};
    gemm128_dbuf(hb + (size_t)m0*DD, Wob + (size_t)n0*DD, As, Bs, acc, t);

    const int wm = (w>>1)*64, wn = (w&1)*64;
    #pragma unroll
    for (int mf=0; mf<4; mf++){
        int m = m0 + wm + mf*16 + (lane>>4)*4;
        #pragma unroll
        for (int nf=0; nf<4; nf++){
            int n = n0 + wn + nf*16 + (lane&15);
            float bias = bo[n];
            #pragma unroll
            for (int r=0; r<4; r++)
                out[(size_t)(m+r)*DD + n] = fmaxf(acc[mf][nf][r] + bias, 0.0f);
        }
    }
}

// ------------------------------------------------------------------
// scores (merged modes): 192x192x256 GEMM per block, bf16 out (/16).
// MODE = blockIdx.y:
//   0 (t1): block (b,i): S1[b,i,j,l]  = q[b,i,j,:].k[b,i,l,:]/16
//   1 (t2): block (b,j): S2T[b,j,i,l] = q[b,i,j,:].k[b,l,j,:]/16
// ------------------------------------------------------------------
__global__ __launch_bounds__(512, 2) void k_scores(
    const u16* __restrict__ q, const u16* __restrict__ kmat,
    u16* __restrict__ S1, u16* __restrict__ S2T)
{
    __shared__ u16 As[2][NG*64];
    __shared__ u16 Bs[2][NG*64];
    const int MODE = blockIdx.y;
    const int z = blockIdx.x, b = z/NG, r = z%NG;
    const int t = threadIdx.x, lane = t&63, w = t>>6;
    const int wm = (w&3)*48, wn = (w>>2)*96;
    const size_t astr = MODE ? (size_t)NG*DD : (size_t)DD;
    const u16* Ab = MODE ? q    + ((size_t)b*NN2 + r)*DD : q    + ((size_t)b*NG + r)*NG*DD;
    const u16* Bb = MODE ? kmat + ((size_t)b*NN2 + r)*DD : kmat + ((size_t)b*NG + r)*NG*DD;

    f32x4 acc[3][6];
    #pragma unroll
    for (int i=0;i<3;i++)
        #pragma unroll
        for (int j=0;j<6;j++) acc[i][j] = f32x4{0.f,0.f,0.f,0.f};

    int offA[3], offB[6];
    #pragma unroll
    for (int mf=0; mf<3; mf++){
        int x = wm + mf*16 + (lane&15);
        offA[mf] = x*64 + (((lane>>4)<<3) ^ swz3(x));
    }
    #pragma unroll
    for (int nf=0; nf<6; nf++){
        int x = wn + nf*16 + (lane&15);
        offB[nf] = x*64 + (((lane>>4)<<3) ^ swz3(x));
    }

    auto stage = [&](int buf, int k0){
        #pragma unroll
        for (int rr=0; rr<3; rr++){
            int c = t + rr*512;
            int x = c>>3, l8e = (c&7)<<3;
            size_t ro = (size_t)x*astr + k0;
            gl_lds16(Ab + ro + (l8e ^ swz3(x)), &As[buf][c*8]);
            gl_lds16(Bb + ro + (l8e ^ swz3(x)), &Bs[buf][c*8]);
        }
    };

    stage(0, 0);
    for (int ks=0; ks<4; ks++){
        if (ks<3){
            stage((ks+1)&1, (ks+1)*64);
            asm volatile("s_waitcnt vmcnt(6)" ::: "memory");
        } else {
            asm volatile("s_waitcnt vmcnt(0)" ::: "memory");
        }
        __builtin_amdgcn_s_barrier();
        const u16* A = &As[ks&1][0];
        const u16* B = &Bs[ks&1][0];
        #pragma unroll
        for (int kk=0; kk<2; kk++){
            bf16x8 a[3];
            #pragma unroll
            for (int mf=0; mf<3; mf++) a[mf] = *(const bf16x8*)(A + (offA[mf]^(kk<<5)));
            #pragma unroll
            for (int nf=0; nf<6; nf++){
                bf16x8 bf = *(const bf16x8*)(B + (offB[nf]^(kk<<5)));
                #pragma unroll
                for (int mf=0; mf<3; mf++)
                    acc[mf][nf] = __builtin_amdgcn_mfma_f32_16x16x32_bf16(a[mf], bf, acc[mf][nf], 0, 0, 0);
            }
        }
        __builtin_amdgcn_s_barrier();
    }

    u16* outb = (MODE ? S2T : S1) + ((size_t)b*NG + r)*NN2;
    #pragma unroll
    for (int mf=0; mf<3; mf++){
        #pragma unroll
        for (int nf=0; nf<6; nf++){
            int lcol = wn + nf*16 + (lane&15);
            #pragma unroll
            for (int r4=0; r4<4; r4++){
                int x = wm + mf*16 + (lane>>4)*4 + r4;   // j (M0) or i (M1)
                outb[(size_t)x*NG + lcol] = f2bfu(acc[mf][nf][r4]*0.0625f);
            }
        }
    }
}

// ------------------------------------------------------------------
// softmax over l: s = S1[b,i,j,l] + S2T[b,j,i,l] + biassym[b,i,l]
// ------------------------------------------------------------------
__global__ __launch_bounds__(256) void k_softmax(
    const u16* __restrict__ S1, const u16* __restrict__ S2T,
    const float* __restrict__ biassym,
    u16* __restrict__ alpha, u16* __restrict__ alphaT)
{
    int rr   = blockIdx.x*4 + (threadIdx.x >> 6);   // i*NG + j
    int lane = threadIdx.x & 63;
    int b = blockIdx.y;
    int i = rr / NG, j = rr % NG;
    const u16* r1 = S1  + ((size_t)b*NN2 + rr)*NG;
    const u16* r2 = S2T + ((size_t)b*NN2 + (size_t)j*NG + i)*NG;
    const float* bs = biassym + ((size_t)b*NG + i)*NG;
    float vals[3];
    float mx = -1e30f;
    #pragma unroll
    for (int tt=0; tt<3; tt++){
        int l = lane + tt*64;
        float s = bfu2f(r1[l]) + bfu2f(r2[l]) + bs[l];
        vals[tt] = s;
        mx = fmaxf(mx, s);
    }
    #pragma unroll
    for (int off=32; off; off>>=1) mx = fmaxf(mx, __shfl_xor(mx, off));
    float sum = 0.f;
    #pragma unroll
    for (int tt=0; tt<3; tt++){ vals[tt] = __expf(vals[tt]-mx); sum += vals[tt]; }
    #pragma unroll
    for (int off=32; off; off>>=1) sum += __shfl_xor(sum, off);
    float inv = 1.0f/sum;
    u16* arow1 = alpha  + ((size_t)b*NN2 + rr)*NG;
    u16* arow2 = alphaT + ((size_t)b*NN2 + (size_t)j*NG + i)*NG;
    #pragma unroll
    for (int tt=0; tt<3; tt++){
        u16 vq = f2bfu(vals[tt]*inv);
        arow1[lane + tt*64] = vq;
        arow2[lane + tt*64] = vq;
    }
}

// ------------------------------------------------------------------
// attnout: block (bi, dhalf): out[192 j x 128 d] = A1@V1^T + A2@V2^T, gated.
// Grid swizzled so both dhalf blocks of a bi land on the same XCD.
// ------------------------------------------------------------------
__global__ __launch_bounds__(512, 4) void k_attnout(
    const u16* __restrict__ alpha, const u16* __restrict__ alphaT,
    const u16* __restrict__ vb, const u16* __restrict__ gb, u16* __restrict__ hb)
{
    __shared__ u16 AsL[2][NG*64];    // 2 x 24.0 KiB
    __shared__ u16 Vs[128*64];       // 16 KiB
    const int z = blockIdx.x;
    const int xcd = z & 7, s = z >> 3;          // s in [0,96)
    const int bi = xcd*48 + (s>>1), dh = s & 1;
    const int b = bi/NG, i = bi%NG;
    const int dbase = dh*128;
    const int t = threadIdx.x, lane = t&63, w = t>>6;
    const int wm = (w&1)*96, wn = (w>>1)*32;

    const u16* Abase0 = alpha  + (size_t)bi*NN2;
    const u16* Abase1 = alphaT + (size_t)bi*NN2;
    const u16* V0 = vb + (size_t)bi*NG*DD + dbase;             // + l*DD
    const u16* V1 = vb + ((size_t)b*NG*NG + i)*DD + dbase;     // + l*NG*DD

    f32x4 acc[6][2];
    #pragma unroll
    for (int m=0;m<6;m++)
        #pragma unroll
        for (int n=0;n<2;n++) acc[m][n] = f32x4{0.f,0.f,0.f,0.f};

    int offA[6], offB[2];
    #pragma unroll
    for (int mf=0; mf<6; mf++){
        int j = wm + mf*16 + (lane&15);
        offA[mf] = j*64 + (((lane>>4)<<3) ^ swz3(j));
    }
    #pragma unroll
    for (int nf=0; nf<2; nf++){
        int d = wn + nf*16 + (lane&15);
        offB[nf] = d*64 + (((lane>>4)<<3) ^ swz3(d));
    }

    int4 vr[2];
    auto stageA = [&](int u, int buf){
        const u16* Ab = (u>=3) ? Abase1 : Abase0;
        int ls = (u>=3 ? u-3 : u)*64;
        #pragma unroll
        for (int rr=0; rr<3; rr++){
            int c = t + rr*512;
            int j = c>>3, l8e = (c&7)<<3;
            gl_lds16(Ab + (size_t)j*NG + ls + (l8e ^ swz3(j)), &AsL[buf][c*8]);
        }
    };
    auto loadV = [&](int u){
        int p = (u>=3), ls = (u>=3 ? u-3 : u)*64;
        #pragma unroll
        for (int rr=0; rr<2; rr++){
            int c = t + rr*512;
            int l = ls + (c>>4), d0 = (c&15)*8;
            const u16* src = p ? (V1 + (size_t)l*NG*DD + d0) : (V0 + (size_t)l*DD + d0);
            vr[rr] = *(const int4*)src;
        }
    };

    stageA(0, 0);
    loadV(0);
    for (int u=0; u<6; u++){
        #pragma unroll
        for (int rr=0; rr<2; rr++){
            int c = t + rr*512;
            int l = c>>4;
            l &= 63;
            int d0 = (c&15)*8, c3 = c&7;
            ushort* vp = (ushort*)&vr[rr];
            #pragma unroll
            for (int qd=0; qd<8; qd++)
                Vs[(d0+qd)*64 + (l ^ ((qd^c3)<<3))] = vp[qd];
        }
        if (u<5){ stageA(u+1, (u+1)&1); loadV(u+1); }
        asm volatile("s_waitcnt lgkmcnt(0)" ::: "memory");
        __builtin_amdgcn_s_barrier();
        const u16* A = &AsL[u&1][0];
        #pragma unroll
        for (int kk=0; kk<2; kk++){
            bf16x8 bfr[2];
            #pragma unroll
            for (int nf=0; nf<2; nf++) bfr[nf] = *(const bf16x8*)(Vs + (offB[nf]^(kk<<5)));
            #pragma unroll
            for (int mf=0; mf<6; mf++){
                bf16x8 afr = *(const bf16x8*)(A + (offA[mf]^(kk<<5)));
                acc[mf][0] = __builtin_amdgcn_mfma_f32_16x16x32_bf16(afr, bfr[0], acc[mf][0], 0, 0, 0);
                acc[mf][1] = __builtin_amdgcn_mfma_f32_16x16x32_bf16(afr, bfr[1], acc[mf][1], 0, 0, 0);
            }
        }
        __builtin_amdgcn_s_barrier();
    }

    #pragma unroll
    for (int mf=0; mf<6; mf++){
        #pragma unroll
        for (int nf=0; nf<2; nf++){
            #pragma unroll
            for (int r4=0; r4<4; r4++){
                int j = wm + mf*16 + (lane>>4)*4 + r4;
                int d = dbase + wn + nf*16 + (lane&15);
                size_t idx = ((size_t)bi*NG + j)*DD + d;
                hb[idx] = f2bfu(bfu2f(gb[idx]) * acc[mf][nf][r4]);
            }
        }
    }
}

// ------------------------------------------------------------------
extern "C" void kernel_launch(void* const* d_in, const int* in_sizes, int n_in,
                              void* d_out, int out_size, void* d_ws, size_t ws_size,
                              hipStream_t stream)
{
    const float* E  = (const float*)d_in[0];
    const float* Wq = (const float*)d_in[1];  const float* bq = (const float*)d_in[2];
    const float* Wk = (const float*)d_in[3];  const float* bk = (const float*)d_in[4];
    const float* Wv = (const float*)d_in[5];  const float* bv = (const float*)d_in[6];
    const float* Wb = (const float*)d_in[7];  const float* bb = (const float*)d_in[8];
    const float* Wg = (const float*)d_in[9];  const float* bg = (const float*)d_in[10];
    const float* Wo = (const float*)d_in[11]; const float* bo = (const float*)d_in[12];
    float* out = (float*)d_out;

    const size_t BF = (size_t)MT*DD*2;              // 37,748,736
    const size_t SC = (size_t)NB*NG*NG*NG*4;        // 56,623,104
    char* ws = (char*)d_ws;
    u16* Eb  = (u16*)ws;
    u16* S1  = (u16*)ws;                            // 28.3 MB
    u16* S2T = (u16*)(ws + SC/2);                   // 28.3 MB
    u16* hb  = (u16*)ws;
    u16* qb = (u16*)(ws + SC);           u16* alpha  = qb;
    u16* kb = (u16*)(ws + SC + BF);      u16* alphaT = kb;
    u16* vb = (u16*)(ws + SC + 2*BF);
    u16* gb = (u16*)(ws + SC + 3*BF);
    size_t tail = SC + 4*BF;
    float* bm      = (float*)(ws + tail); tail += (size_t)MT*4;
    float* biassym = (float*)(ws + tail); tail += (size_t)MT*4;
    u16* Wcat      = (u16*)(ws + tail);   tail += (size_t)1024*DD*2;
    u16* Wob       = (u16*)(ws + tail);   tail += (size_t)DD*DD*2;
    float* biascat = (float*)(ws + tail); tail += 1024*4;
    (void)ws_size;

    k_cast_w   <<<dim3(256), 256, 0, stream>>>(Wq,Wk,Wv,Wg,Wo, bq,bk,bv,bg, Wcat, Wob, biascat);
    k_cast_eb  <<<dim3(9216), 256, 0, stream>>>(E, Wb, bb, Eb, bm);
    k_proj_mfma<<<dim3(4608), 256, 0, stream>>>(Eb, Wcat, biascat, qb, kb, vb, gb);
    k_bias_sym <<<dim3(NN2/256, NB), 256, 0, stream>>>(bm, biassym);
    k_scores   <<<dim3(NB*NG, 2), 512, 0, stream>>>(qb, kb, S1, S2T);
    k_softmax  <<<dim3(NN2/4, NB), 256, 0, stream>>>(S1, S2T, biassym, alpha, alphaT);
    k_attnout  <<<dim3(NB*NG*2), 512, 0, stream>>>(alpha, alphaT, vb, gb, hb);
    k_final_mfma<<<dim3(1152), 256, 0, stream>>>(hb, Wob, bo, out);
}

// Round 14
// 238.539 us; speedup vs baseline: 1.1062x; 1.1062x over previous
//
#include <hip/hip_runtime.h>
#include <hip/hip_bf16.h>

typedef __hip_bfloat16 bf16;
typedef unsigned short u16;
typedef __attribute__((ext_vector_type(8))) short bf16x8;
typedef __attribute__((ext_vector_type(4))) float f32x4;

#define NB   2
#define NG   192
#define DD   256
#define NN2  (NG*NG)          // 36864
#define MT   (NB*NN2)         // 73728

static __device__ __forceinline__ float bfu2f(u16 u){
    return __uint_as_float(((unsigned)u) << 16);
}
static __device__ __forceinline__ u16 f2bfu(float f){
    bf16 h = __float2bfloat16(f);
    return *(u16*)&h;
}

// async global->LDS, 16B/lane. LDS dest: wave-uniform base + lane*16 (linear).
static __device__ __forceinline__ void gl_lds16(const void* g, void* l){
    __builtin_amdgcn_global_load_lds(
        (const __attribute__((address_space(1))) unsigned int*)g,
        (__attribute__((address_space(3))) unsigned int*)l, 16, 0, 0);
}
// XOR swizzle (element-index bits 3-5)
static __device__ __forceinline__ int swz3(int x){ return ((x ^ (x>>3)) & 7) << 3; }

// ------------------------------------------------------------------
// cast E -> bf16, fused with bmat GEMV
// ------------------------------------------------------------------
__global__ __launch_bounds__(256) void k_cast_eb(
    const float* __restrict__ E, const float* __restrict__ Wb,
    const float* __restrict__ bb, u16* __restrict__ Eb, float* __restrict__ bm)
{
    const int t = threadIdx.x;
    size_t base = (size_t)blockIdx.x*2048 + t*8;
    float4 x = *(const float4*)(E+base);
    float4 y = *(const float4*)(E+base+4);
    ushort4 a; a.x=f2bfu(x.x); a.y=f2bfu(x.y); a.z=f2bfu(x.z); a.w=f2bfu(x.w);
    ushort4 b; b.x=f2bfu(y.x); b.y=f2bfu(y.y); b.z=f2bfu(y.z); b.w=f2bfu(y.w);
    *(ushort4*)(Eb+base)   = a;
    *(ushort4*)(Eb+base+4) = b;
    const int l32 = t & 31;
    float4 w0 = ((const float4*)Wb)[l32*2];
    float4 w1 = ((const float4*)Wb)[l32*2+1];
    float s = x.x*w0.x + x.y*w0.y + x.z*w0.z + x.w*w0.w
            + y.x*w1.x + y.y*w1.y + y.z*w1.z + y.w*w1.w;
    #pragma unroll
    for (int off=1; off<32; off<<=1) s += __shfl_xor(s, off);
    if (l32 == 0) bm[blockIdx.x*8 + (t>>5)] = s + bb[0];
}

__global__ __launch_bounds__(256) void k_cast_w(
    const float* __restrict__ Wq, const float* __restrict__ Wk,
    const float* __restrict__ Wv, const float* __restrict__ Wg,
    const float* __restrict__ Wo,
    const float* __restrict__ bq, const float* __restrict__ bk,
    const float* __restrict__ bv, const float* __restrict__ bg,
    u16* __restrict__ Wcat, u16* __restrict__ Wob, float* __restrict__ biascat)
{
    int e = blockIdx.x*256 + threadIdx.x;      // 65536 total
    Wcat[e]          = f2bfu(Wq[e]);
    Wcat[65536 + e]  = f2bfu(Wk[e]);
    Wcat[131072 + e] = f2bfu(Wv[e]);
    Wcat[196608 + e] = f2bfu(Wg[e]);
    Wob[e]           = f2bfu(Wo[e]);
    if (e < 1024){
        int p = e>>8, r = e&255;
        const float* bp = p==0?bq : p==1?bk : p==2?bv : bg;
        biascat[e] = bp[r];
    }
}

// biassym[b,i,l] = bm[b,i,l] + bm[b,l,i]
__global__ __launch_bounds__(256) void k_bias_sym(
    const float* __restrict__ bm, float* __restrict__ biassym)
{
    int rem = blockIdx.x*256 + threadIdx.x;     // < 36864
    int b = blockIdx.y;
    int i = rem / NG, l = rem % NG;
    biassym[(size_t)b*NN2 + rem] = bm[(size_t)b*NN2 + rem] + bm[(size_t)b*NN2 + l*NG + i];
}

// ------------------------------------------------------------------
// 128x128 MFMA tile, K=256, BK=32 double-buffered + counted vmcnt(4).
// SWAPPED operands: mfma(b, a, acc) -> thread holds m=lane&15 (fixed),
// n=(lane>>4)*4+r (4 consecutive) => vectorizable epilogue stores.
// ------------------------------------------------------------------
static __device__ __forceinline__ void gemm128_dbuf_sw(
    const u16* __restrict__ A, const u16* __restrict__ B,
    u16* As, u16* Bs, f32x4 acc[4][4], int t)
{
    const int lane = t & 63, w = t >> 6;
    const int wm = (w>>1)*64, wn = (w&1)*64;
    int offA[4], offB[4];
    #pragma unroll
    for (int f=0; f<4; f++){
        int ra = wm + f*16 + (lane&15);
        offA[f] = ra*32 + (((lane>>4) ^ ((ra>>1)&3)) << 3);
        int rb = wn + f*16 + (lane&15);
        offB[f] = rb*32 + (((lane>>4) ^ ((rb>>1)&3)) << 3);
    }
    auto stage = [&](int buf, int k0){
        #pragma unroll
        for (int it=0; it<2; it++){
            int c = it*256 + t;
            int row = c >> 2;
            int ks  = (c&3) ^ ((row>>1)&3);
            gl_lds16(A + (size_t)row*DD + k0 + ks*8, As + buf*4096 + c*8);
            gl_lds16(B + (size_t)row*DD + k0 + ks*8, Bs + buf*4096 + c*8);
        }
    };
    stage(0, 0);
    for (int ks=0; ks<8; ks++){
        if (ks<7){
            stage((ks+1)&1, (ks+1)*32);
            asm volatile("s_waitcnt vmcnt(4)" ::: "memory");
        } else {
            asm volatile("s_waitcnt vmcnt(0)" ::: "memory");
        }
        __builtin_amdgcn_s_barrier();
        const u16* Ab = As + (ks&1)*4096;
        const u16* Bb = Bs + (ks&1)*4096;
        bf16x8 a[4], b[4];
        #pragma unroll
        for (int f=0; f<4; f++) a[f] = *(const bf16x8*)(Ab + offA[f]);
        #pragma unroll
        for (int f=0; f<4; f++) b[f] = *(const bf16x8*)(Bb + offB[f]);
        #pragma unroll
        for (int mf=0; mf<4; mf++)
            #pragma unroll
            for (int nf=0; nf<4; nf++)
                acc[mf][nf] = __builtin_amdgcn_mfma_f32_16x16x32_bf16(b[nf], a[mf], acc[mf][nf], 0, 0, 0);
        __builtin_amdgcn_s_barrier();
    }
}

// fused q/k/v/g projection: Eb[73728x256] @ Wcat^T[1024x256]
// grid 4608 1D; blk&7 ~ XCD; n-tile innermost for L2 reuse of Wcat.
// Swapped fragments -> 16x ushort4 (8B) stores per thread (was 64x 2B).
__global__ __launch_bounds__(256) void k_proj_mfma(
    const u16* __restrict__ Eb, const u16* __restrict__ Wcat,
    const float* __restrict__ biascat,
    u16* __restrict__ qb, u16* __restrict__ kb,
    u16* __restrict__ vb, u16* __restrict__ gb)
{
    __shared__ u16 As[2*4096];
    __shared__ u16 Bs[2*4096];
    const int blk = blockIdx.x;
    const int xj = blk & 7, xi = blk >> 3;          // xi in [0,576)
    const int m0 = (xj*72 + (xi>>3)) * 128;
    const int n0 = (xi & 7) * 128;
    const int t = threadIdx.x, lane = t&63, w = t>>6;
    f32x4 acc[4][4];
    #pragma unroll
    for (int i=0;i<4;i++)
        #pragma unroll
        for (int j=0;j<4;j++) acc[i][j] = f32x4{0.f,0.f,0.f,0.f};
    gemm128_dbuf_sw(Eb + (size_t)m0*DD, Wcat + (size_t)n0*DD, As, Bs, acc, t);

    const int p = n0 >> 8;
    u16* outp = p==0?qb : p==1?kb : p==2?vb : gb;
    const int wm = (w>>1)*64, wn = (w&1)*64;
    #pragma unroll
    for (int mf=0; mf<4; mf++){
        int m = m0 + wm + mf*16 + (lane&15);
        #pragma unroll
        for (int nf=0; nf<4; nf++){
            int gn = n0 + wn + nf*16 + (lane>>4)*4;     // 4-aligned
            float4 b4 = *(const float4*)(biascat + gn);
            int col = gn & 255;
            u16 o[4];
            float v0 = acc[mf][nf][0] + b4.x;
            float v1 = acc[mf][nf][1] + b4.y;
            float v2 = acc[mf][nf][2] + b4.z;
            float v3 = acc[mf][nf][3] + b4.w;
            if (p==3){
                v0 = 1.0f/(1.0f+__expf(-v0)); v1 = 1.0f/(1.0f+__expf(-v1));
                v2 = 1.0f/(1.0f+__expf(-v2)); v3 = 1.0f/(1.0f+__expf(-v3));
            }
            o[0]=f2bfu(v0); o[1]=f2bfu(v1); o[2]=f2bfu(v2); o[3]=f2bfu(v3);
            *(ushort4*)(outp + (size_t)m*DD + col) = *(ushort4*)o;
        }
    }
}

// final: out = relu(hb @ Wob^T + bo), f32; grid 1152 1D swizzled.
// Swapped fragments -> 16x f32x4 (16B) stores per thread (was 64x 4B).
__global__ __launch_bounds__(256) void k_final_mfma(
    const u16* __restrict__ hb, const u16* __restrict__ Wob,
    const float* __restrict__ bo, float* __restrict__ out)
{
    __shared__ u16 As[2*4096];
    __shared__ u16 Bs[2*4096];
    const int blk = blockIdx.x;
    const int xj = blk & 7, xi = blk >> 3;          // xi in [0,144)
    const int m0 = (xj*72 + (xi>>1)) * 128;
    const int n0 = (xi & 1) * 128;
    const int t = threadIdx.x, lane = t&63, w = t>>6;
    f32x4 acc[4][4];
    #pragma unroll
    for (int i=0;i<4;i++)
        #pragma unroll
        for (int j=0;j<4;j++) acc[i][j] = f32x4{0.f,0.f,0.f,0.f};
    gemm128_dbuf_sw(hb + (size_t)m0*DD, Wob + (size_t)n0*DD, As, Bs, acc, t);

    const int wm = (w>>1)*64, wn = (w&1)*64;
    #pragma unroll
    for (int mf=0; mf<4; mf++){
        int m = m0 + wm + mf*16 + (lane&15);
        #pragma unroll
        for (int nf=0; nf<4; nf++){
            int n = n0 + wn + nf*16 + (lane>>4)*4;      // 4-aligned
            float4 b4 = *(const float4*)(bo + n);
            f32x4 v;
            v[0] = fmaxf(acc[mf][nf][0] + b4.x, 0.0f);
            v[1] = fmaxf(acc[mf][nf][1] + b4.y, 0.0f);
            v[2] = fmaxf(acc[mf][nf][2] + b4.z, 0.0f);
            v[3] = fmaxf(acc[mf][nf][3] + b4.w, 0.0f);
            *(f32x4*)(out + (size_t)m*DD + n) = v;
        }
    }
}

// ------------------------------------------------------------------
// scores (merged modes): 192x192x256 GEMM per block, bf16 out (/16).
// MODE = blockIdx.y. Swapped fragments -> ushort4 stores.
// ------------------------------------------------------------------
__global__ __launch_bounds__(512, 2) void k_scores(
    const u16* __restrict__ q, const u16* __restrict__ kmat,
    u16* __restrict__ S1, u16* __restrict__ S2T)
{
    __shared__ u16 As[2][NG*64];
    __shared__ u16 Bs[2][NG*64];
    const int MODE = blockIdx.y;
    const int z = blockIdx.x, b = z/NG, r = z%NG;
    const int t = threadIdx.x, lane = t&63, w = t>>6;
    const int wm = (w&3)*48, wn = (w>>2)*96;
    const size_t astr = MODE ? (size_t)NG*DD : (size_t)DD;
    const u16* Ab = MODE ? q    + ((size_t)b*NN2 + r)*DD : q    + ((size_t)b*NG + r)*NG*DD;
    const u16* Bb = MODE ? kmat + ((size_t)b*NN2 + r)*DD : kmat + ((size_t)b*NG + r)*NG*DD;

    f32x4 acc[3][6];
    #pragma unroll
    for (int i=0;i<3;i++)
        #pragma unroll
        for (int j=0;j<6;j++) acc[i][j] = f32x4{0.f,0.f,0.f,0.f};

    int offA[3], offB[6];
    #pragma unroll
    for (int mf=0; mf<3; mf++){
        int x = wm + mf*16 + (lane&15);
        offA[mf] = x*64 + (((lane>>4)<<3) ^ swz3(x));
    }
    #pragma unroll
    for (int nf=0; nf<6; nf++){
        int x = wn + nf*16 + (lane&15);
        offB[nf] = x*64 + (((lane>>4)<<3) ^ swz3(x));
    }

    auto stage = [&](int buf, int k0){
        #pragma unroll
        for (int rr=0; rr<3; rr++){
            int c = t + rr*512;
            int x = c>>3, l8e = (c&7)<<3;
            size_t ro = (size_t)x*astr + k0;
            gl_lds16(Ab + ro + (l8e ^ swz3(x)), &As[buf][c*8]);
            gl_lds16(Bb + ro + (l8e ^ swz3(x)), &Bs[buf][c*8]);
        }
    };

    stage(0, 0);
    for (int ks=0; ks<4; ks++){
        if (ks<3){
            stage((ks+1)&1, (ks+1)*64);
            asm volatile("s_waitcnt vmcnt(6)" ::: "memory");
        } else {
            asm volatile("s_waitcnt vmcnt(0)" ::: "memory");
        }
        __builtin_amdgcn_s_barrier();
        const u16* A = &As[ks&1][0];
        const u16* B = &Bs[ks&1][0];
        #pragma unroll
        for (int kk=0; kk<2; kk++){
            bf16x8 a[3];
            #pragma unroll
            for (int mf=0; mf<3; mf++) a[mf] = *(const bf16x8*)(A + (offA[mf]^(kk<<5)));
            #pragma unroll
            for (int nf=0; nf<6; nf++){
                bf16x8 bf = *(const bf16x8*)(B + (offB[nf]^(kk<<5)));
                #pragma unroll
                for (int mf=0; mf<3; mf++)
                    acc[mf][nf] = __builtin_amdgcn_mfma_f32_16x16x32_bf16(bf, a[mf], acc[mf][nf], 0, 0, 0);
            }
        }
        __builtin_amdgcn_s_barrier();
    }

    u16* outb = (MODE ? S2T : S1) + ((size_t)b*NG + r)*NN2;
    #pragma unroll
    for (int mf=0; mf<3; mf++){
        int x = wm + mf*16 + (lane&15);           // j (M0) or i (M1)
        #pragma unroll
        for (int nf=0; nf<6; nf++){
            int lbase = wn + nf*16 + (lane>>4)*4;  // 4-aligned
            u16 o[4];
            o[0]=f2bfu(acc[mf][nf][0]*0.0625f);
            o[1]=f2bfu(acc[mf][nf][1]*0.0625f);
            o[2]=f2bfu(acc[mf][nf][2]*0.0625f);
            o[3]=f2bfu(acc[mf][nf][3]*0.0625f);
            *(ushort4*)(outb + (size_t)x*NG + lbase) = *(ushort4*)o;
        }
    }
}

// ------------------------------------------------------------------
// softmax over l: s = S1[b,i,j,l] + S2T[b,j,i,l] + biassym[b,i,l]
// ------------------------------------------------------------------
__global__ __launch_bounds__(256) void k_softmax(
    const u16* __restrict__ S1, const u16* __restrict__ S2T,
    const float* __restrict__ biassym,
    u16* __restrict__ alpha, u16* __restrict__ alphaT)
{
    int rr   = blockIdx.x*4 + (threadIdx.x >> 6);   // i*NG + j
    int lane = threadIdx.x & 63;
    int b = blockIdx.y;
    int i = rr / NG, j = rr % NG;
    const u16* r1 = S1  + ((size_t)b*NN2 + rr)*NG;
    const u16* r2 = S2T + ((size_t)b*NN2 + (size_t)j*NG + i)*NG;
    const float* bs = biassym + ((size_t)b*NG + i)*NG;
    float vals[3];
    float mx = -1e30f;
    #pragma unroll
    for (int tt=0; tt<3; tt++){
        int l = lane + tt*64;
        float s = bfu2f(r1[l]) + bfu2f(r2[l]) + bs[l];
        vals[tt] = s;
        mx = fmaxf(mx, s);
    }
    #pragma unroll
    for (int off=32; off; off>>=1) mx = fmaxf(mx, __shfl_xor(mx, off));
    float sum = 0.f;
    #pragma unroll
    for (int tt=0; tt<3; tt++){ vals[tt] = __expf(vals[tt]-mx); sum += vals[tt]; }
    #pragma unroll
    for (int off=32; off; off>>=1) sum += __shfl_xor(sum, off);
    float inv = 1.0f/sum;
    u16* arow1 = alpha  + ((size_t)b*NN2 + rr)*NG;
    u16* arow2 = alphaT + ((size_t)b*NN2 + (size_t)j*NG + i)*NG;
    #pragma unroll
    for (int tt=0; tt<3; tt++){
        u16 vq = f2bfu(vals[tt]*inv);
        arow1[lane + tt*64] = vq;
        arow2[lane + tt*64] = vq;
    }
}

// ------------------------------------------------------------------
// attnout: block (bi, dhalf): out[192 j x 128 d] = A1@V1^T + A2@V2^T, gated.
// Grid swizzled so both dhalf blocks of a bi land on the same XCD.
// Swapped fragments -> ushort4 gate-loads + stores.
// ------------------------------------------------------------------
__global__ __launch_bounds__(512, 4) void k_attnout(
    const u16* __restrict__ alpha, const u16* __restrict__ alphaT,
    const u16* __restrict__ vb, const u16* __restrict__ gb, u16* __restrict__ hb)
{
    __shared__ u16 AsL[2][NG*64];    // 2 x 24.0 KiB
    __shared__ u16 Vs[128*64];       // 16 KiB
    const int z = blockIdx.x;
    const int xcd = z & 7, s = z >> 3;          // s in [0,96)
    const int bi = xcd*48 + (s>>1), dh = s & 1;
    const int b = bi/NG, i = bi%NG;
    const int dbase = dh*128;
    const int t = threadIdx.x, lane = t&63, w = t>>6;
    const int wm = (w&1)*96, wn = (w>>1)*32;

    const u16* Abase0 = alpha  + (size_t)bi*NN2;
    const u16* Abase1 = alphaT + (size_t)bi*NN2;
    const u16* V0 = vb + (size_t)bi*NG*DD + dbase;             // + l*DD
    const u16* V1 = vb + ((size_t)b*NG*NG + i)*DD + dbase;     // + l*NG*DD

    f32x4 acc[6][2];
    #pragma unroll
    for (int m=0;m<6;m++)
        #pragma unroll
        for (int n=0;n<2;n++) acc[m][n] = f32x4{0.f,0.f,0.f,0.f};

    int offA[6], offB[2];
    #pragma unroll
    for (int mf=0; mf<6; mf++){
        int j = wm + mf*16 + (lane&15);
        offA[mf] = j*64 + (((lane>>4)<<3) ^ swz3(j));
    }
    #pragma unroll
    for (int nf=0; nf<2; nf++){
        int d = wn + nf*16 + (lane&15);
        offB[nf] = d*64 + (((lane>>4)<<3) ^ swz3(d));
    }

    int4 vr[2];
    auto stageA = [&](int u, int buf){
        const u16* Ab = (u>=3) ? Abase1 : Abase0;
        int ls = (u>=3 ? u-3 : u)*64;
        #pragma unroll
        for (int rr=0; rr<3; rr++){
            int c = t + rr*512;
            int j = c>>3, l8e = (c&7)<<3;
            gl_lds16(Ab + (size_t)j*NG + ls + (l8e ^ swz3(j)), &AsL[buf][c*8]);
        }
    };
    auto loadV = [&](int u){
        int p = (u>=3), ls = (u>=3 ? u-3 : u)*64;
        #pragma unroll
        for (int rr=0; rr<2; rr++){
            int c = t + rr*512;
            int l = ls + (c>>4), d0 = (c&15)*8;
            const u16* src = p ? (V1 + (size_t)l*NG*DD + d0) : (V0 + (size_t)l*DD + d0);
            vr[rr] = *(const int4*)src;
        }
    };

    stageA(0, 0);
    loadV(0);
    for (int u=0; u<6; u++){
        #pragma unroll
        for (int rr=0; rr<2; rr++){
            int c = t + rr*512;
            int l = c>>4;
            l &= 63;
            int d0 = (c&15)*8, c3 = c&7;
            ushort* vp = (ushort*)&vr[rr];
            #pragma unroll
            for (int qd=0; qd<8; qd++)
                Vs[(d0+qd)*64 + (l ^ ((qd^c3)<<3))] = vp[qd];
        }
        if (u<5){ stageA(u+1, (u+1)&1); loadV(u+1); }
        asm volatile("s_waitcnt lgkmcnt(0)" ::: "memory");
        __builtin_amdgcn_s_barrier();
        const u16* A = &AsL[u&1][0];
        #pragma unroll
        for (int kk=0; kk<2; kk++){
            bf16x8 bfr[2];
            #pragma unroll
            for (int nf=0; nf<2; nf++) bfr[nf] = *(const bf16x8*)(Vs + (offB[nf]^(kk<<5)));
            #pragma unroll
            for (int mf=0; mf<6; mf++){
                bf16x8 afr = *(const bf16x8*)(A + (offA[mf]^(kk<<5)));
                acc[mf][0] = __builtin_amdgcn_mfma_f32_16x16x32_bf16(bfr[0], afr, acc[mf][0], 0, 0, 0);
                acc[mf][1] = __builtin_amdgcn_mfma_f32_16x16x32_bf16(bfr[1], afr, acc[mf][1], 0, 0, 0);
            }
        }
        __builtin_amdgcn_s_barrier();
    }

    #pragma unroll
    for (int mf=0; mf<6; mf++){
        int j = wm + mf*16 + (lane&15);
        #pragma unroll
        for (int nf=0; nf<2; nf++){
            int d = dbase + wn + nf*16 + (lane>>4)*4;     // 4-aligned
            size_t idx = ((size_t)bi*NG + j)*DD + d;
            ushort4 g4 = *(const ushort4*)(gb + idx);
            u16 o[4];
            o[0] = f2bfu(bfu2f(g4.x) * acc[mf][nf][0]);
            o[1] = f2bfu(bfu2f(g4.y) * acc[mf][nf][1]);
            o[2] = f2bfu(bfu2f(g4.z) * acc[mf][nf][2]);
            o[3] = f2bfu(bfu2f(g4.w) * acc[mf][nf][3]);
            *(ushort4*)(hb + idx) = *(ushort4*)o;
        }
    }
}

// ------------------------------------------------------------------
extern "C" void kernel_launch(void* const* d_in, const int* in_sizes, int n_in,
                              void* d_out, int out_size, void* d_ws, size_t ws_size,
                              hipStream_t stream)
{
    const float* E  = (const float*)d_in[0];
    const float* Wq = (const float*)d_in[1];  const float* bq = (const float*)d_in[2];
    const float* Wk = (const float*)d_in[3];  const float* bk = (const float*)d_in[4];
    const float* Wv = (const float*)d_in[5];  const float* bv = (const float*)d_in[6];
    const float* Wb = (const float*)d_in[7];  const float* bb = (const float*)d_in[8];
    const float* Wg = (const float*)d_in[9];  const float* bg = (const float*)d_in[10];
    const float* Wo = (const float*)d_in[11]; const float* bo = (const float*)d_in[12];
    float* out = (float*)d_out;

    const size_t BF = (size_t)MT*DD*2;              // 37,748,736
    const size_t SC = (size_t)NB*NG*NG*NG*4;        // 56,623,104
    char* ws = (char*)d_ws;
    u16* Eb  = (u16*)ws;
    u16* S1  = (u16*)ws;                            // 28.3 MB
    u16* S2T = (u16*)(ws + SC/2);                   // 28.3 MB
    u16* hb  = (u16*)ws;
    u16* qb = (u16*)(ws + SC);           u16* alpha  = qb;
    u16* kb = (u16*)(ws + SC + BF);      u16* alphaT = kb;
    u16* vb = (u16*)(ws + SC + 2*BF);
    u16* gb = (u16*)(ws + SC + 3*BF);
    size_t tail = SC + 4*BF;
    float* bm      = (float*)(ws + tail); tail += (size_t)MT*4;
    float* biassym = (float*)(ws + tail); tail += (size_t)MT*4;
    u16* Wcat      = (u16*)(ws + tail);   tail += (size_t)1024*DD*2;
    u16* Wob       = (u16*)(ws + tail);   tail += (size_t)DD*DD*2;
    float* biascat = (float*)(ws + tail); tail += 1024*4;
    (void)ws_size;

    k_cast_w   <<<dim3(256), 256, 0, stream>>>(Wq,Wk,Wv,Wg,Wo, bq,bk,bv,bg, Wcat, Wob, biascat);
    k_cast_eb  <<<dim3(9216), 256, 0, stream>>>(E, Wb, bb, Eb, bm);
    k_proj_mfma<<<dim3(4608), 256, 0, stream>>>(Eb, Wcat, biascat, qb, kb, vb, gb);
    k_bias_sym <<<dim3(NN2/256, NB), 256, 0, stream>>>(bm, biassym);
    k_scores   <<<dim3(NB*NG, 2), 512, 0, stream>>>(qb, kb, S1, S2T);
    k_softmax  <<<dim3(NN2/4, NB), 256, 0, stream>>>(S1, S2T, biassym, alpha, alphaT);
    k_attnout  <<<dim3(NB*NG*2), 512, 0, stream>>>(alpha, alphaT, vb, gb, hb);
    k_final_mfma<<<dim3(1152), 256, 0, stream>>>(hb, Wob, bo, out);
}

// Round 15
// 222.574 us; speedup vs baseline: 1.1855x; 1.0717x over previous
//
#include <hip/hip_runtime.h>
#include <hip/hip_bf16.h>

typedef __hip_bfloat16 bf16;
typedef unsigned short u16;
typedef __attribute__((ext_vector_type(8))) short bf16x8;
typedef __attribute__((ext_vector_type(4))) float f32x4;

#define NB   2
#define NG   192
#define DD   256
#define NN2  (NG*NG)          // 36864
#define MT   (NB*NN2)         // 73728

static __device__ __forceinline__ float bfu2f(u16 u){
    return __uint_as_float(((unsigned)u) << 16);
}
static __device__ __forceinline__ u16 f2bfu(float f){
    bf16 h = __float2bfloat16(f);
    return *(u16*)&h;
}

// async global->LDS, 16B/lane. LDS dest: wave-uniform base + lane*16 (linear).
static __device__ __forceinline__ void gl_lds16(const void* g, void* l){
    __builtin_amdgcn_global_load_lds(
        (const __attribute__((address_space(1))) unsigned int*)g,
        (__attribute__((address_space(3))) unsigned int*)l, 16, 0, 0);
}
// XOR swizzle (element-index bits 3-5)
static __device__ __forceinline__ int swz3(int x){ return ((x ^ (x>>3)) & 7) << 3; }

// ------------------------------------------------------------------
// cast E -> bf16, fused with bmat GEMV
// ------------------------------------------------------------------
__global__ __launch_bounds__(256) void k_cast_eb(
    const float* __restrict__ E, const float* __restrict__ Wb,
    const float* __restrict__ bb, u16* __restrict__ Eb, float* __restrict__ bm)
{
    const int t = threadIdx.x;
    size_t base = (size_t)blockIdx.x*2048 + t*8;
    float4 x = *(const float4*)(E+base);
    float4 y = *(const float4*)(E+base+4);
    ushort4 a; a.x=f2bfu(x.x); a.y=f2bfu(x.y); a.z=f2bfu(x.z); a.w=f2bfu(x.w);
    ushort4 b; b.x=f2bfu(y.x); b.y=f2bfu(y.y); b.z=f2bfu(y.z); b.w=f2bfu(y.w);
    *(ushort4*)(Eb+base)   = a;
    *(ushort4*)(Eb+base+4) = b;
    const int l32 = t & 31;
    float4 w0 = ((const float4*)Wb)[l32*2];
    float4 w1 = ((const float4*)Wb)[l32*2+1];
    float s = x.x*w0.x + x.y*w0.y + x.z*w0.z + x.w*w0.w
            + y.x*w1.x + y.y*w1.y + y.z*w1.z + y.w*w1.w;
    #pragma unroll
    for (int off=1; off<32; off<<=1) s += __shfl_xor(s, off);
    if (l32 == 0) bm[blockIdx.x*8 + (t>>5)] = s + bb[0];
}

__global__ __launch_bounds__(256) void k_cast_w(
    const float* __restrict__ Wq, const float* __restrict__ Wk,
    const float* __restrict__ Wv, const float* __restrict__ Wg,
    const float* __restrict__ Wo,
    const float* __restrict__ bq, const float* __restrict__ bk,
    const float* __restrict__ bv, const float* __restrict__ bg,
    u16* __restrict__ Wcat, u16* __restrict__ Wob, float* __restrict__ biascat)
{
    int e = blockIdx.x*256 + threadIdx.x;      // 65536 total
    Wcat[e]          = f2bfu(Wq[e]);
    Wcat[65536 + e]  = f2bfu(Wk[e]);
    Wcat[131072 + e] = f2bfu(Wv[e]);
    Wcat[196608 + e] = f2bfu(Wg[e]);
    Wob[e]           = f2bfu(Wo[e]);
    if (e < 1024){
        int p = e>>8, r = e&255;
        const float* bp = p==0?bq : p==1?bk : p==2?bv : bg;
        biascat[e] = bp[r];
    }
}

// ------------------------------------------------------------------
// 128x128 MFMA tile, K=256, BK=32 double-buffered + counted vmcnt(4).
// (round-5/8 proven: 0 bank conflicts)
// ------------------------------------------------------------------
static __device__ __forceinline__ void gemm128_dbuf(
    const u16* __restrict__ A, const u16* __restrict__ B,
    u16* As, u16* Bs, f32x4 acc[4][4], int t)
{
    const int lane = t & 63, w = t >> 6;
    const int wm = (w>>1)*64, wn = (w&1)*64;
    int offA[4], offB[4];
    #pragma unroll
    for (int f=0; f<4; f++){
        int ra = wm + f*16 + (lane&15);
        offA[f] = ra*32 + (((lane>>4) ^ ((ra>>1)&3)) << 3);
        int rb = wn + f*16 + (lane&15);
        offB[f] = rb*32 + (((lane>>4) ^ ((rb>>1)&3)) << 3);
    }
    auto stage = [&](int buf, int k0){
        #pragma unroll
        for (int it=0; it<2; it++){
            int c = it*256 + t;
            int row = c >> 2;
            int ks  = (c&3) ^ ((row>>1)&3);
            gl_lds16(A + (size_t)row*DD + k0 + ks*8, As + buf*4096 + c*8);
            gl_lds16(B + (size_t)row*DD + k0 + ks*8, Bs + buf*4096 + c*8);
        }
    };
    stage(0, 0);
    for (int ks=0; ks<8; ks++){
        if (ks<7){
            stage((ks+1)&1, (ks+1)*32);
            asm volatile("s_waitcnt vmcnt(4)" ::: "memory");
        } else {
            asm volatile("s_waitcnt vmcnt(0)" ::: "memory");
        }
        __builtin_amdgcn_s_barrier();
        const u16* Ab = As + (ks&1)*4096;
        const u16* Bb = Bs + (ks&1)*4096;
        bf16x8 a[4], b[4];
        #pragma unroll
        for (int f=0; f<4; f++) a[f] = *(const bf16x8*)(Ab + offA[f]);
        #pragma unroll
        for (int f=0; f<4; f++) b[f] = *(const bf16x8*)(Bb + offB[f]);
        #pragma unroll
        for (int mf=0; mf<4; mf++)
            #pragma unroll
            for (int nf=0; nf<4; nf++)
                acc[mf][nf] = __builtin_amdgcn_mfma_f32_16x16x32_bf16(a[mf], b[nf], acc[mf][nf], 0, 0, 0);
        __builtin_amdgcn_s_barrier();
    }
}

// fused q/k/v/g projection: Eb[73728x256] @ Wcat^T[1024x256]
// grid 4608 1D; blk&7 ~ XCD; n-tile innermost for L2 reuse of Wcat
__global__ __launch_bounds__(256) void k_proj_mfma(
    const u16* __restrict__ Eb, const u16* __restrict__ Wcat,
    const float* __restrict__ biascat,
    u16* __restrict__ qb, u16* __restrict__ kb,
    u16* __restrict__ vb, u16* __restrict__ gb)
{
    __shared__ u16 As[2*4096];
    __shared__ u16 Bs[2*4096];
    const int blk = blockIdx.x;
    const int xj = blk & 7, xi = blk >> 3;          // xi in [0,576)
    const int m0 = (xj*72 + (xi>>3)) * 128;
    const int n0 = (xi & 7) * 128;
    const int t = threadIdx.x, lane = t&63, w = t>>6;
    f32x4 acc[4][4];
    #pragma unroll
    for (int i=0;i<4;i++)
        #pragma unroll
        for (int j=0;j<4;j++) acc[i][j] = f32x4{0.f,0.f,0.f,0.f};
    gemm128_dbuf(Eb + (size_t)m0*DD, Wcat + (size_t)n0*DD, As, Bs, acc, t);

    const int p = n0 >> 8;
    u16* outp = p==0?qb : p==1?kb : p==2?vb : gb;
    const int wm = (w>>1)*64, wn = (w&1)*64;
    #pragma unroll
    for (int mf=0; mf<4; mf++){
        int m = m0 + wm + mf*16 + (lane>>4)*4;
        #pragma unroll
        for (int nf=0; nf<4; nf++){
            int gn = n0 + wn + nf*16 + (lane&15);
            float bias = biascat[gn];
            int col = gn & 255;
            #pragma unroll
            for (int r=0; r<4; r++){
                float v = acc[mf][nf][r] + bias;
                if (p==3) v = 1.0f/(1.0f+__expf(-v));
                outp[(size_t)(m+r)*DD + col] = f2bfu(v);
            }
        }
    }
}

// final: out = relu(hb @ Wob^T + bo), f32; grid 1152 1D swizzled
__global__ __launch_bounds__(256) void k_final_mfma(
    const u16* __restrict__ hb, const u16* __restrict__ Wob,
    const float* __restrict__ bo, float* __restrict__ out)
{
    __shared__ u16 As[2*4096];
    __shared__ u16 Bs[2*4096];
    const int blk = blockIdx.x;
    const int xj = blk & 7, xi = blk >> 3;          // xi in [0,144)
    const int m0 = (xj*72 + (xi>>1)) * 128;
    const int n0 = (xi & 1) * 128;
    const int t = threadIdx.x, lane = t&63, w = t>>6;
    f32x4 acc[4][4];
    #pragma unroll
    for (int i=0;i<4;i++)
        #pragma unroll
        for (int j=0;j<4;j++) acc[i][j] = f32x4{0.f,0.f,0.f,0.f};
    gemm128_dbuf(hb + (size_t)m0*DD, Wob + (size_t)n0*DD, As, Bs, acc, t);

    const int wm = (w>>1)*64, wn = (w&1)*64;
    #pragma unroll
    for (int mf=0; mf<4; mf++){
        int m = m0 + wm + mf*16 + (lane>>4)*4;
        #pragma unroll
        for (int nf=0; nf<4; nf++){
            int n = n0 + wn + nf*16 + (lane&15);
            float bias = bo[n];
            #pragma unroll
            for (int r=0; r<4; r++)
                out[(size_t)(m+r)*DD + n] = fmaxf(acc[mf][nf][r] + bias, 0.0f);
        }
    }
}

// ------------------------------------------------------------------
// scores (merged modes): 192x192x256 GEMM per block, bf16 out (/16).
// MODE = blockIdx.y:
//   0 (t1): block (b,i): S1[b,i,j,l]  = q.k/16 + bm[b,i,l] + bm[b,l,i]
//   1 (t2): block (b,j): S2T[b,j,i,l] = q.k/16
// ------------------------------------------------------------------
__global__ __launch_bounds__(512, 2) void k_scores(
    const u16* __restrict__ q, const u16* __restrict__ kmat,
    const float* __restrict__ bm,
    u16* __restrict__ S1, u16* __restrict__ S2T)
{
    __shared__ u16 As[2][NG*64];
    __shared__ u16 Bs[2][NG*64];
    const int MODE = blockIdx.y;
    const int z = blockIdx.x, b = z/NG, r = z%NG;
    const int t = threadIdx.x, lane = t&63, w = t>>6;
    const int wm = (w&3)*48, wn = (w>>2)*96;
    const size_t astr = MODE ? (size_t)NG*DD : (size_t)DD;
    const u16* Ab = MODE ? q    + ((size_t)b*NN2 + r)*DD : q    + ((size_t)b*NG + r)*NG*DD;
    const u16* Bb = MODE ? kmat + ((size_t)b*NN2 + r)*DD : kmat + ((size_t)b*NG + r)*NG*DD;

    f32x4 acc[3][6];
    #pragma unroll
    for (int i=0;i<3;i++)
        #pragma unroll
        for (int j=0;j<6;j++) acc[i][j] = f32x4{0.f,0.f,0.f,0.f};

    int offA[3], offB[6];
    #pragma unroll
    for (int mf=0; mf<3; mf++){
        int x = wm + mf*16 + (lane&15);
        offA[mf] = x*64 + (((lane>>4)<<3) ^ swz3(x));
    }
    #pragma unroll
    for (int nf=0; nf<6; nf++){
        int x = wn + nf*16 + (lane&15);
        offB[nf] = x*64 + (((lane>>4)<<3) ^ swz3(x));
    }

    auto stage = [&](int buf, int k0){
        #pragma unroll
        for (int rr=0; rr<3; rr++){
            int c = t + rr*512;
            int x = c>>3, l8e = (c&7)<<3;
            size_t ro = (size_t)x*astr + k0;
            gl_lds16(Ab + ro + (l8e ^ swz3(x)), &As[buf][c*8]);
            gl_lds16(Bb + ro + (l8e ^ swz3(x)), &Bs[buf][c*8]);
        }
    };

    stage(0, 0);
    for (int ks=0; ks<4; ks++){
        if (ks<3){
            stage((ks+1)&1, (ks+1)*64);
            asm volatile("s_waitcnt vmcnt(6)" ::: "memory");
        } else {
            asm volatile("s_waitcnt vmcnt(0)" ::: "memory");
        }
        __builtin_amdgcn_s_barrier();
        const u16* A = &As[ks&1][0];
        const u16* B = &Bs[ks&1][0];
        #pragma unroll
        for (int kk=0; kk<2; kk++){
            bf16x8 a[3];
            #pragma unroll
            for (int mf=0; mf<3; mf++) a[mf] = *(const bf16x8*)(A + (offA[mf]^(kk<<5)));
            #pragma unroll
            for (int nf=0; nf<6; nf++){
                bf16x8 bf = *(const bf16x8*)(B + (offB[nf]^(kk<<5)));
                #pragma unroll
                for (int mf=0; mf<3; mf++)
                    acc[mf][nf] = __builtin_amdgcn_mfma_f32_16x16x32_bf16(a[mf], bf, acc[mf][nf], 0, 0, 0);
            }
        }
        __builtin_amdgcn_s_barrier();
    }

    u16* outb = (MODE ? S2T : S1) + ((size_t)b*NG + r)*NN2;
    const float* bmb = bm + (size_t)b*NN2;
    #pragma unroll
    for (int mf=0; mf<3; mf++){
        #pragma unroll
        for (int nf=0; nf<6; nf++){
            int lcol = wn + nf*16 + (lane&15);
            float bias = MODE ? 0.f : (bmb[(size_t)r*NG + lcol] + bmb[(size_t)lcol*NG + r]);
            #pragma unroll
            for (int r4=0; r4<4; r4++){
                int x = wm + mf*16 + (lane>>4)*4 + r4;   // j (M0) or i (M1)
                outb[(size_t)x*NG + lcol] = f2bfu(acc[mf][nf][r4]*0.0625f + bias);
            }
        }
    }
}

// ------------------------------------------------------------------
// softmax over l: s = S1[b,i,j,l] + S2T[b,j,i,l]  (bias already in S1)
// writes bf16 alpha only (alphaT eliminated)
// ------------------------------------------------------------------
__global__ __launch_bounds__(256) void k_softmax(
    const u16* __restrict__ S1, const u16* __restrict__ S2T,
    u16* __restrict__ alpha)
{
    int rr   = blockIdx.x*4 + (threadIdx.x >> 6);   // i*NG + j
    int lane = threadIdx.x & 63;
    int b = blockIdx.y;
    int i = rr / NG, j = rr % NG;
    const u16* r1 = S1  + ((size_t)b*NN2 + rr)*NG;
    const u16* r2 = S2T + ((size_t)b*NN2 + (size_t)j*NG + i)*NG;
    float vals[3];
    float mx = -1e30f;
    #pragma unroll
    for (int tt=0; tt<3; tt++){
        int l = lane + tt*64;
        float s = bfu2f(r1[l]) + bfu2f(r2[l]);
        vals[tt] = s;
        mx = fmaxf(mx, s);
    }
    #pragma unroll
    for (int off=32; off; off>>=1) mx = fmaxf(mx, __shfl_xor(mx, off));
    float sum = 0.f;
    #pragma unroll
    for (int tt=0; tt<3; tt++){ vals[tt] = __expf(vals[tt]-mx); sum += vals[tt]; }
    #pragma unroll
    for (int off=32; off; off>>=1) sum += __shfl_xor(sum, off);
    float inv = 1.0f/sum;
    u16* arow1 = alpha + ((size_t)b*NN2 + rr)*NG;
    #pragma unroll
    for (int tt=0; tt<3; tt++)
        arow1[lane + tt*64] = f2bfu(vals[tt]*inv);
}

// ------------------------------------------------------------------
// attnout: block (bi, dhalf): out[192 j x 128 d] = A1@V1^T + A2@V2^T, gated.
// Pass-2 A operand read DIRECTLY from alpha with row stride NN2
// (alpha[b,j,i,l]); alphaT buffer eliminated.
// Grid swizzled so both dhalf blocks of a bi land on the same XCD.
// ------------------------------------------------------------------
__global__ __launch_bounds__(512, 4) void k_attnout(
    const u16* __restrict__ alpha,
    const u16* __restrict__ vb, const u16* __restrict__ gb, u16* __restrict__ hb)
{
    __shared__ u16 AsL[2][NG*64];    // 2 x 24.0 KiB
    __shared__ u16 Vs[128*64];       // 16 KiB
    const int z = blockIdx.x;
    const int xcd = z & 7, s = z >> 3;          // s in [0,96)
    const int bi = xcd*48 + (s>>1), dh = s & 1;
    const int b = bi/NG, i = bi%NG;
    const int dbase = dh*128;
    const int t = threadIdx.x, lane = t&63, w = t>>6;
    const int wm = (w&1)*96, wn = (w>>1)*32;

    const u16* Abase0 = alpha + (size_t)bi*NN2;                // row j: +j*NG
    const u16* Abase1 = alpha + ((size_t)b*NN2 + i)*NG;        // row j: +j*NN2
    const u16* V0 = vb + (size_t)bi*NG*DD + dbase;             // + l*DD
    const u16* V1 = vb + ((size_t)b*NG*NG + i)*DD + dbase;     // + l*NG*DD

    f32x4 acc[6][2];
    #pragma unroll
    for (int m=0;m<6;m++)
        #pragma unroll
        for (int n=0;n<2;n++) acc[m][n] = f32x4{0.f,0.f,0.f,0.f};

    int offA[6], offB[2];
    #pragma unroll
    for (int mf=0; mf<6; mf++){
        int j = wm + mf*16 + (lane&15);
        offA[mf] = j*64 + (((lane>>4)<<3) ^ swz3(j));
    }
    #pragma unroll
    for (int nf=0; nf<2; nf++){
        int d = wn + nf*16 + (lane&15);
        offB[nf] = d*64 + (((lane>>4)<<3) ^ swz3(d));
    }

    int4 vr[2];
    auto stageA = [&](int u, int buf){
        const u16* Ab = (u>=3) ? Abase1 : Abase0;
        const size_t astrd = (u>=3) ? (size_t)NN2 : (size_t)NG;
        int ls = (u>=3 ? u-3 : u)*64;
        #pragma unroll
        for (int rr=0; rr<3; rr++){
            int c = t + rr*512;
            int j = c>>3, l8e = (c&7)<<3;
            gl_lds16(Ab + (size_t)j*astrd + ls + (l8e ^ swz3(j)), &AsL[buf][c*8]);
        }
    };
    auto loadV = [&](int u){
        int p = (u>=3), ls = (u>=3 ? u-3 : u)*64;
        #pragma unroll
        for (int rr=0; rr<2; rr++){
            int c = t + rr*512;
            int l = ls + (c>>4), d0 = (c&15)*8;
            const u16* src = p ? (V1 + (size_t)l*NG*DD + d0) : (V0 + (size_t)l*DD + d0);
            vr[rr] = *(const int4*)src;
        }
    };

    stageA(0, 0);
    loadV(0);
    for (int u=0; u<6; u++){
        #pragma unroll
        for (int rr=0; rr<2; rr++){
            int c = t + rr*512;
            int l = c>>4;
            l &= 63;
            int d0 = (c&15)*8, c3 = c&7;
            ushort* vp = (ushort*)&vr[rr];
            #pragma unroll
            for (int qd=0; qd<8; qd++)
                Vs[(d0+qd)*64 + (l ^ ((qd^c3)<<3))] = vp[qd];
        }
        if (u<5){ stageA(u+1, (u+1)&1); loadV(u+1); }
        asm volatile("s_waitcnt lgkmcnt(0)" ::: "memory");
        __builtin_amdgcn_s_barrier();
        const u16* A = &AsL[u&1][0];
        #pragma unroll
        for (int kk=0; kk<2; kk++){
            bf16x8 bfr[2];
            #pragma unroll
            for (int nf=0; nf<2; nf++) bfr[nf] = *(const bf16x8*)(Vs + (offB[nf]^(kk<<5)));
            #pragma unroll
            for (int mf=0; mf<6; mf++){
                bf16x8 afr = *(const bf16x8*)(A + (offA[mf]^(kk<<5)));
                acc[mf][0] = __builtin_amdgcn_mfma_f32_16x16x32_bf16(afr, bfr[0], acc[mf][0], 0, 0, 0);
                acc[mf][1] = __builtin_amdgcn_mfma_f32_16x16x32_bf16(afr, bfr[1], acc[mf][1], 0, 0, 0);
            }
        }
        __builtin_amdgcn_s_barrier();
    }

    #pragma unroll
    for (int mf=0; mf<6; mf++){
        #pragma unroll
        for (int nf=0; nf<2; nf++){
            #pragma unroll
            for (int r4=0; r4<4; r4++){
                int j = wm + mf*16 + (lane>>4)*4 + r4;
                int d = dbase + wn + nf*16 + (lane&15);
                size_t idx = ((size_t)bi*NG + j)*DD + d;
                hb[idx] = f2bfu(bfu2f(gb[idx]) * acc[mf][nf][r4]);
            }
        }
    }
}

// ------------------------------------------------------------------
extern "C" void kernel_launch(void* const* d_in, const int* in_sizes, int n_in,
                              void* d_out, int out_size, void* d_ws, size_t ws_size,
                              hipStream_t stream)
{
    const float* E  = (const float*)d_in[0];
    const float* Wq = (const float*)d_in[1];  const float* bq = (const float*)d_in[2];
    const float* Wk = (const float*)d_in[3];  const float* bk = (const float*)d_in[4];
    const float* Wv = (const float*)d_in[5];  const float* bv = (const float*)d_in[6];
    const float* Wb = (const float*)d_in[7];  const float* bb = (const float*)d_in[8];
    const float* Wg = (const float*)d_in[9];  const float* bg = (const float*)d_in[10];
    const float* Wo = (const float*)d_in[11]; const float* bo = (const float*)d_in[12];
    float* out = (float*)d_out;

    const size_t BF = (size_t)MT*DD*2;              // 37,748,736
    const size_t SC = (size_t)NB*NG*NG*NG*4;        // 56,623,104
    char* ws = (char*)d_ws;
    u16* Eb  = (u16*)ws;
    u16* S1  = (u16*)ws;                            // 28.3 MB
    u16* S2T = (u16*)(ws + SC/2);                   // 28.3 MB
    u16* hb  = (u16*)ws;
    u16* qb = (u16*)(ws + SC);           u16* alpha = qb;
    u16* kb = (u16*)(ws + SC + BF);
    u16* vb = (u16*)(ws + SC + 2*BF);
    u16* gb = (u16*)(ws + SC + 3*BF);
    size_t tail = SC + 4*BF;
    float* bm      = (float*)(ws + tail); tail += (size_t)MT*4;
    u16* Wcat      = (u16*)(ws + tail);   tail += (size_t)1024*DD*2;
    u16* Wob       = (u16*)(ws + tail);   tail += (size_t)DD*DD*2;
    float* biascat = (float*)(ws + tail); tail += 1024*4;
    (void)ws_size;

    k_cast_w   <<<dim3(256), 256, 0, stream>>>(Wq,Wk,Wv,Wg,Wo, bq,bk,bv,bg, Wcat, Wob, biascat);
    k_cast_eb  <<<dim3(9216), 256, 0, stream>>>(E, Wb, bb, Eb, bm);
    k_proj_mfma<<<dim3(4608), 256, 0, stream>>>(Eb, Wcat, biascat, qb, kb, vb, gb);
    k_scores   <<<dim3(NB*NG, 2), 512, 0, stream>>>(qb, kb, bm, S1, S2T);
    k_softmax  <<<dim3(NN2/4, NB), 256, 0, stream>>>(S1, S2T, alpha);
    k_attnout  <<<dim3(NB*NG*2), 512, 0, stream>>>(alpha, vb, gb, hb);
    k_final_mfma<<<dim3(1152), 256, 0, stream>>>(hb, Wob, bo, out);
}